// Round 10
// baseline (200.950 us; speedup 1.0000x reference)
//
#include <hip/hip_runtime.h>

#define N_ELEM 4096
#define BLOCK 256
#define PER 16             // elems per thread
#define NG (PER / 2)       // v2f groups per thread
#define NWAVE (BLOCK / 64)
#define NITER 40
#define CAPACITY 600.0f
#define DAMPING 1e-3f
// 5-level long-step homotopy (R9): mu = 4^-it for it<5, then 1e-3. Final
// output is the unique mu=1e-3 barrier minimizer -> path-independent; the
// m<eps exit gate guarantees convergence before stopping.
#define MU_FINAL_IT 5
// R7: m's fp32 noise floor is ~1e-5; 1e-3 is safely above it and bounds the
// discarded tail movement far under the 2e-2 tolerance.
#define CONV_EPS 1e-3f

typedef float v2f __attribute__((ext_vector_type(2)));
union F4V2 { float4 f4; v2f v[2]; };

__device__ __forceinline__ float raw_rcp(float a) { return __builtin_amdgcn_rcpf(a); }
__device__ __forceinline__ v2f pk_rcp(v2f a) {
    v2f r; r.x = raw_rcp(a.x); r.y = raw_rcp(a.y); return r;
}
__device__ __forceinline__ v2f pk_max(v2f a, v2f b) { return __builtin_elementwise_max(a, b); }

__device__ __forceinline__ float bcast_first(float v) {
    return __uint_as_float(__builtin_amdgcn_readfirstlane(__float_as_uint(v)));
}

// Fused 3-value block sum-reduction. ONE barrier; parity buffer from caller.
__device__ __forceinline__ void block_reduce3(float& a, float& b, float& c, float* buf) {
    #pragma unroll
    for (int off = 32; off > 0; off >>= 1) {
        a += __shfl_xor(a, off, 64);
        b += __shfl_xor(b, off, 64);
        c += __shfl_xor(c, off, 64);
    }
    const int wave = threadIdx.x >> 6;
    if ((threadIdx.x & 63) == 0) {
        buf[3 * wave] = a; buf[3 * wave + 1] = b; buf[3 * wave + 2] = c;
    }
    __syncthreads();
    float a0 = 0.0f, b0 = 0.0f, c0 = 0.0f;
    #pragma unroll
    for (int i = 0; i < NWAVE; ++i) {
        a0 += buf[3 * i]; b0 += buf[3 * i + 1]; c0 += buf[3 * i + 2];
    }
    a = a0; b = b0; c = c0;
}

__device__ __forceinline__ float block_reduce_max(float v, float* buf) {
    #pragma unroll
    for (int off = 32; off > 0; off >>= 1) v = fmaxf(v, __shfl_xor(v, off, 64));
    const int wave = threadIdx.x >> 6;
    if ((threadIdx.x & 63) == 0) buf[wave] = v;
    __syncthreads();
    float m = buf[0];
    #pragma unroll
    for (int i = 1; i < NWAVE; ++i) m = fmaxf(m, buf[i]);
    return m;
}

// R10: PER-ELEMENT step lengths. Global fraction-to-boundary made one
// boundary-hugging element clip the whole row's step (R9: ~13 final-mu
// sweeps at contraction ~0.6). With diagonal H, each x_k update is a damped
// 1-D Newton step on a strictly convex 1-D barrier -> converges at its own
// rate; lambda takes its exact Schur step. F2 is now computed explicitly
// (s3) since steps are non-uniform. The m<eps gate still verifies global
// convergence before exit, so correctness is independent of the dynamics.
__global__ __launch_bounds__(BLOCK, 4) void ipm_knapsack_kernel(
        const float* __restrict__ costs,
        const float* __restrict__ weights,
        float* __restrict__ out) {
    __shared__ float4 c4s[N_ELEM / 4];    // 16 KB: -costs (this row)
    __shared__ float4 w4s[N_ELEM / 4];    // 16 KB: weights
    __shared__ float ldsA[2][3 * NWAVE];  // parity-buffered reduce scratch
    __shared__ float ldsM[2][NWAVE];
    __shared__ float ldsF[3 * NWAVE];     // init + final-refine reduce
    const int row = blockIdx.x;
    const int t   = threadIdx.x;

    v2f x[NG], g[NG], wih[NG], tinv[NG];

    // ---- Stage c (negated) and w into LDS; accumulate sum(w) ----
    const float4* cg = reinterpret_cast<const float4*>(costs + (size_t)row * N_ELEM);
    const float4* wg = reinterpret_cast<const float4*>(weights);
    float ws = 0.0f, z1 = 0.0f, z2 = 0.0f;
    #pragma unroll
    for (int j = 0; j < NG / 2; ++j) {
        float4 cc = cg[t + BLOCK * j];
        float4 ww = wg[t + BLOCK * j];
        cc.x = -cc.x; cc.y = -cc.y; cc.z = -cc.z; cc.w = -cc.w;
        c4s[t + BLOCK * j] = cc;
        w4s[t + BLOCK * j] = ww;
        ws += (ww.x + ww.y) + (ww.z + ww.w);
    }
    block_reduce3(ws, z1, z2, ldsF);  // barrier also orders LDS staging

    const float x0 = CAPACITY / ws;
    #pragma unroll
    for (int k = 0; k < NG; ++k) { v2f x0v = {x0, x0}; x[k] = x0v; }
    float lam = 0.0f;

    // Packed phase A: u=x(1-x); one rcp -> 1/u and 1/H=u^3*r.
    // s1 = sum (w/H)F1, s2 = sum w^2/H, s3 = sum w*x (explicit F2).
    auto phaseA = [&](float mu, float& s1, float& s2, float& s3) {
        const float m2mu = -2.0f * mu;
        v2f s1v = {0.0f, 0.0f}, s2v = {0.0f, 0.0f}, s3v = {0.0f, 0.0f};
        #pragma unroll
        for (int j = 0; j < NG / 2; ++j) {
            F4V2 cv, wv;
            cv.f4 = c4s[t + BLOCK * j];
            wv.f4 = w4s[t + BLOCK * j];
            #pragma unroll
            for (int h = 0; h < 2; ++h) {
                const int k = 2 * j + h;
                const v2f xk = x[k], wk = wv.v[h];
                const v2f p  = 1.0f - xk;
                const v2f u  = xk * p;
                const v2f d  = m2mu * u + mu;         // mu*(1-2u) > 0
                const v2f r  = pk_rcp(u * d);
                const v2f ti = r * d;                 // 1/u
                const v2f q  = xk - p;                // 2x-1
                const v2f f1 = (mu * ti) * q + (lam * wk + cv.v[h]);
                const v2f u2 = u * u;
                const v2f iH = (u2 * u) * r;          // 1/H
                const v2f gk = f1 * iH;
                const v2f wi = wk * iH;
                s1v = wk * gk + s1v;
                s2v = wk * wi + s2v;
                s3v = wk * xk + s3v;
                g[k] = gk; wih[k] = wi; tinv[k] = ti;
            }
        }
        s1 = s1v.x + s1v.y; s2 = s2v.x + s2v.y; s3 = s3v.x + s3v.y;
    };

    for (int it = 0; it < NITER; ++it) {
        const float mu = (it < MU_FINAL_IT)
                       ? __uint_as_float((unsigned)(127 - 2 * it) << 23) : DAMPING;
        float s1, s2, s3;
        phaseA(mu, s1, s2, s3);
        block_reduce3(s1, s2, s3, ldsA[(it + 1) & 1]);
        const float f2   = s3 - CAPACITY;
        const float dlam = bcast_first((f2 - s1) * raw_rcp(s2));

        // ---- Phase B: per-element damped update ----
        // dxn = -dx; m_k = max(-dxn/(1-x), dxn/x) (>=0);
        // alpha_k = 0.99/max(m_k, 0.99)  (full step when interior);
        // x_k += -alpha_k*dxn. Global m only feeds the exit gate.
        const v2f c099 = {0.99f, 0.99f};
        v2f mv = {0.0f, 0.0f};
        #pragma unroll
        for (int k = 0; k < NG; ++k) {
            const v2f dxn = dlam * wih[k] + g[k];
            const v2f ti  = tinv[k];
            const v2f xt  = x[k] * ti;                // 1/(1-x)
            const v2f pt  = ti - xt;                  // 1/x
            const v2f mk  = pk_max((-dxn) * xt, dxn * pt);
            mv = pk_max(mv, mk);
            const v2f ak  = 0.99f * pk_rcp(pk_max(mk, c099));
            x[k] = (-ak) * dxn + x[k];
        }
        float m = fmaxf(mv.x, mv.y);
        m = block_reduce_max(m, ldsM[it & 1]);        // block-uniform
        lam += dlam;                                  // exact Schur step

        // Exit once mu is final and the whole row's steps are tiny: the
        // mu=1e-3 minimizer is unique => converged == reference output.
        if (it >= MU_FINAL_IT && m < CONV_EPS) break;
    }

    // ---- Final KKT refine at mu = DAMPING: out = x - (g + dlam*wih) ----
    float s1, s2, s3;
    phaseA(DAMPING, s1, s2, s3);
    block_reduce3(s1, s2, s3, ldsF);
    const float dlam = bcast_first(((s3 - CAPACITY) - s1) * raw_rcp(s2));

    float4* o4 = reinterpret_cast<float4*>(out + (size_t)row * N_ELEM);
    #pragma unroll
    for (int j = 0; j < NG / 2; ++j) {
        F4V2 ov;
        #pragma unroll
        for (int h = 0; h < 2; ++h) {
            const int k = 2 * j + h;
            const v2f dxn = dlam * wih[k] + g[k];
            ov.v[h] = x[k] - dxn;
        }
        o4[t + BLOCK * j] = ov.f4;
    }
}

extern "C" void kernel_launch(void* const* d_in, const int* in_sizes, int n_in,
                              void* d_out, int out_size, void* d_ws, size_t ws_size,
                              hipStream_t stream) {
    const float* costs   = (const float*)d_in[0];
    const float* weights = (const float*)d_in[1];
    float* out = (float*)d_out;
    const int B = in_sizes[0] / N_ELEM;   // 2048 rows
    ipm_knapsack_kernel<<<B, BLOCK, 0, stream>>>(costs, weights, out);
}